// Round 3
// baseline (401.128 us; speedup 1.0000x reference)
//
#include <hip/hip_runtime.h>
#include <hip/hip_bf16.h>

#define B_ 2
#define T_ 2048
#define D_ 1024
#define H_ 16
#define HD_ 64
#define NP_ 3
#define P_ 256

typedef short bf16x8 __attribute__((ext_vector_type(8)));
typedef float f32x4 __attribute__((ext_vector_type(4)));

__device__ __forceinline__ float bf2f(__hip_bfloat16 v) { return __bfloat162float(v); }
__device__ __forceinline__ __hip_bfloat16 f2bf(float v) { return __float2bfloat16(v); }

// ---------------------------------------------------------------------------
// Kernel 0: input dtype detect. fp32 data reinterpreted as bf16 halves shows
// huge-exponent patterns (mantissa low halves); real bf16 N(0,1) never has
// exp >= 0xB8 (|v| >= 2^57). flag=1 -> inputs (and output) are fp32.
// ---------------------------------------------------------------------------
__global__ __launch_bounds__(256) void detect_kernel(
    const unsigned short* __restrict__ xs, int* __restrict__ flag)
{
    __shared__ int cnt;
    if (threadIdx.x == 0) cnt = 0;
    __syncthreads();
    int bad = 0;
    for (int i = threadIdx.x; i < 16384; i += 256) {
        int e = (xs[i] >> 7) & 0xFF;
        if (e >= 0xB8) bad++;
    }
    if (bad) atomicAdd(&cnt, bad);
    __syncthreads();
    if (threadIdx.x == 0) *flag = (cnt >= 8) ? 1 : 0;
}

// src (fp32 or bf16 per flag) -> bf16
__global__ __launch_bounds__(256) void cvt16_kernel(
    const void* __restrict__ src, __hip_bfloat16* __restrict__ dst,
    int n, const int* __restrict__ flag)
{
    int i = blockIdx.x * 256 + threadIdx.x;
    if (i >= n) return;
    dst[i] = (*flag) ? f2bf(((const float*)src)[i])
                     : ((const __hip_bfloat16*)src)[i];
}

// src (fp32 or bf16 per flag) -> fp32
__global__ __launch_bounds__(256) void cvt32_kernel(
    const void* __restrict__ src, float* __restrict__ dst,
    int n, const int* __restrict__ flag)
{
    int i = blockIdx.x * 256 + threadIdx.x;
    if (i >= n) return;
    dst[i] = (*flag) ? ((const float*)src)[i]
                     : bf2f(((const __hip_bfloat16*)src)[i]);
}

// ---------------------------------------------------------------------------
// Kernel 1: h = rmsnorm(x, w) * gamma + beta  (fp32 in, bf16 out for MFMA)
// ---------------------------------------------------------------------------
__global__ __launch_bounds__(256) void rmsnorm1_kernel(
    const float* __restrict__ x,
    const float* __restrict__ gamma,
    const float* __restrict__ beta,
    const float* __restrict__ w,
    const int* __restrict__ flag,
    __hip_bfloat16* __restrict__ out)
{
    int row = blockIdx.x;
    int t = threadIdx.x;
    const float* xr = x + (size_t)row * D_;
    float eps = (*flag) ? 1.1920929e-7f : 0.0078125f;
    float v[4];
    float ss = 0.f;
#pragma unroll
    for (int c = 0; c < 4; c++) {
        v[c] = xr[t * 4 + c];
        ss += v[c] * v[c];
    }
#pragma unroll
    for (int m = 32; m; m >>= 1) ss += __shfl_xor(ss, m, 64);
    __shared__ float red[4];
    int wv = t >> 6;
    if ((t & 63) == 0) red[wv] = ss;
    __syncthreads();
    float tot = red[0] + red[1] + red[2] + red[3];
    float scale = rsqrtf(tot * (1.0f / D_) + eps);
#pragma unroll
    for (int c = 0; c < 4; c++) {
        int e = t * 4 + c;
        out[(size_t)row * D_ + e] = f2bf(v[c] * scale * w[e] * gamma[e] + beta[e]);
    }
}

// ---------------------------------------------------------------------------
// Kernel 2: C = A @ B^T, bf16 out (QKV). 128x128 tile, BK=32, 4 waves 2x2,
// each wave 4x4 mfma tiles of 16x16x32.
// ---------------------------------------------------------------------------
__global__ __launch_bounds__(256) void gemm_bt_bf16_kernel(
    const __hip_bfloat16* __restrict__ A,
    const __hip_bfloat16* __restrict__ Bm,
    __hip_bfloat16* __restrict__ C,
    int M, int N, int K)
{
    __shared__ __attribute__((aligned(16))) __hip_bfloat16 As[128 * 32];
    __shared__ __attribute__((aligned(16))) __hip_bfloat16 Bs[128 * 32];
    int tid = threadIdx.x;
    int bm = blockIdx.y, bn = blockIdx.x;
    int lane = tid & 63, wv = tid >> 6;
    int wm = wv >> 1, wn = wv & 1;
    int q = lane >> 4, mr = lane & 15;

    f32x4 acc[4][4] = {};

    for (int k0 = 0; k0 < K; k0 += 32) {
#pragma unroll
        for (int s = 0; s < 2; s++) {
            int e = (s * 256 + tid) * 8;
            int r = e >> 5, c = e & 31;
            *(bf16x8*)(&As[e]) = *(const bf16x8*)(&A[(size_t)(bm * 128 + r) * K + k0 + c]);
            *(bf16x8*)(&Bs[e]) = *(const bf16x8*)(&Bm[(size_t)(bn * 128 + r) * K + k0 + c]);
        }
        __syncthreads();
        bf16x8 af[4], bfr[4];
#pragma unroll
        for (int i = 0; i < 4; i++)
            af[i] = *(const bf16x8*)(&As[(wm * 64 + i * 16 + mr) * 32 + q * 8]);
#pragma unroll
        for (int j = 0; j < 4; j++)
            bfr[j] = *(const bf16x8*)(&Bs[(wn * 64 + j * 16 + mr) * 32 + q * 8]);
#pragma unroll
        for (int i = 0; i < 4; i++)
#pragma unroll
            for (int j = 0; j < 4; j++)
                acc[i][j] = __builtin_amdgcn_mfma_f32_16x16x32_bf16(af[i], bfr[j], acc[i][j], 0, 0, 0);
        __syncthreads();
    }

#pragma unroll
    for (int i = 0; i < 4; i++)
#pragma unroll
        for (int r = 0; r < 4; r++) {
            int m = bm * 128 + wm * 64 + i * 16 + q * 4 + r;
#pragma unroll
            for (int j = 0; j < 4; j++) {
                int n = bn * 128 + wn * 64 + j * 16 + mr;
                C[(size_t)m * N + n] = f2bf(acc[i][j][r]);
            }
        }
}

// Same GEMM, fp32 residual in + fp32 out (o-proj + residual spine).
__global__ __launch_bounds__(256) void gemm_bt_resid_kernel(
    const __hip_bfloat16* __restrict__ A,
    const __hip_bfloat16* __restrict__ Bm,
    const float* __restrict__ resid,
    float* __restrict__ C,
    int M, int N, int K)
{
    __shared__ __attribute__((aligned(16))) __hip_bfloat16 As[128 * 32];
    __shared__ __attribute__((aligned(16))) __hip_bfloat16 Bs[128 * 32];
    int tid = threadIdx.x;
    int bm = blockIdx.y, bn = blockIdx.x;
    int lane = tid & 63, wv = tid >> 6;
    int wm = wv >> 1, wn = wv & 1;
    int q = lane >> 4, mr = lane & 15;

    f32x4 acc[4][4] = {};

    for (int k0 = 0; k0 < K; k0 += 32) {
#pragma unroll
        for (int s = 0; s < 2; s++) {
            int e = (s * 256 + tid) * 8;
            int r = e >> 5, c = e & 31;
            *(bf16x8*)(&As[e]) = *(const bf16x8*)(&A[(size_t)(bm * 128 + r) * K + k0 + c]);
            *(bf16x8*)(&Bs[e]) = *(const bf16x8*)(&Bm[(size_t)(bn * 128 + r) * K + k0 + c]);
        }
        __syncthreads();
        bf16x8 af[4], bfr[4];
#pragma unroll
        for (int i = 0; i < 4; i++)
            af[i] = *(const bf16x8*)(&As[(wm * 64 + i * 16 + mr) * 32 + q * 8]);
#pragma unroll
        for (int j = 0; j < 4; j++)
            bfr[j] = *(const bf16x8*)(&Bs[(wn * 64 + j * 16 + mr) * 32 + q * 8]);
#pragma unroll
        for (int i = 0; i < 4; i++)
#pragma unroll
            for (int j = 0; j < 4; j++)
                acc[i][j] = __builtin_amdgcn_mfma_f32_16x16x32_bf16(af[i], bfr[j], acc[i][j], 0, 0, 0);
        __syncthreads();
    }

#pragma unroll
    for (int i = 0; i < 4; i++)
#pragma unroll
        for (int r = 0; r < 4; r++) {
            int m = bm * 128 + wm * 64 + i * 16 + q * 4 + r;
#pragma unroll
            for (int j = 0; j < 4; j++) {
                int n = bn * 128 + wn * 64 + j * 16 + mr;
                size_t idx = (size_t)m * N + n;
                C[idx] = resid[idx] + acc[i][j][r];
            }
        }
}

// ---------------------------------------------------------------------------
// Kernel 3: causal flash attention. qkv:[B*T, 3*D] (q|k|v each D, head h at
// cols h*64). One block = 64 queries of one (b,h); wave w owns rows [w*16,+16).
// Layouts (verified m89/m91/m120): A/B frag [idx=lane&15][k=(lane>>4)*8+j],
// C/D col=lane&15, row=(lane>>4)*4+reg.
// ---------------------------------------------------------------------------
__global__ __launch_bounds__(256) void attn_kernel(
    const __hip_bfloat16* __restrict__ qkv,
    __hip_bfloat16* __restrict__ attn_out)
{
    __shared__ __attribute__((aligned(16))) __hip_bfloat16 Qs[64 * 64];
    __shared__ __attribute__((aligned(16))) __hip_bfloat16 Ks[64 * 64];
    __shared__ __attribute__((aligned(16))) __hip_bfloat16 Vts[64 * 64]; // [dim][key]
    __shared__ __attribute__((aligned(16))) __hip_bfloat16 Ps[4 * 16 * 64];

    int qt = blockIdx.x;
    int bh = blockIdx.y;
    int b = bh >> 4, h = bh & 15;
    int tid = threadIdx.x, lane = tid & 63, wv = tid >> 6;
    int q = lane >> 4, mr = lane & 15;

    const size_t rs3 = 3 * D_;
    const __hip_bfloat16* qp = qkv + (size_t)(b * T_) * rs3 + h * HD_;
    const __hip_bfloat16* kp = qp + D_;
    const __hip_bfloat16* vp = qp + 2 * D_;

    {
        int r = tid >> 2, c = (tid & 3) * 16;
        const __hip_bfloat16* src = qp + (size_t)(qt * 64 + r) * rs3 + c;
        *(bf16x8*)(&Qs[r * 64 + c]) = *(const bf16x8*)(src);
        *(bf16x8*)(&Qs[r * 64 + c + 8]) = *(const bf16x8*)(src + 8);
    }

    float m_run[4], l_run[4];
    f32x4 o_acc[4] = {};
#pragma unroll
    for (int r = 0; r < 4; r++) { m_run[r] = -INFINITY; l_run[r] = 0.f; }

    for (int kt = 0; kt <= qt; kt++) {
        __syncthreads();   // protect Ks/Vts reuse; makes Qs visible on iter 0
        {
            int r = tid >> 2, c = (tid & 3) * 16;
            const __hip_bfloat16* src = kp + (size_t)(kt * 64 + r) * rs3 + c;
            *(bf16x8*)(&Ks[r * 64 + c]) = *(const bf16x8*)(src);
            *(bf16x8*)(&Ks[r * 64 + c + 8]) = *(const bf16x8*)(src + 8);
            const __hip_bfloat16* vsrc = vp + (size_t)(kt * 64 + r) * rs3 + c;
#pragma unroll
            for (int cc = 0; cc < 16; cc++)
                Vts[(c + cc) * 64 + r] = vsrc[cc];
        }
        __syncthreads();

        f32x4 s[4] = {};
#pragma unroll
        for (int kk = 0; kk < 2; kk++) {
            bf16x8 aq = *(const bf16x8*)(&Qs[(wv * 16 + mr) * 64 + kk * 32 + q * 8]);
#pragma unroll
            for (int j = 0; j < 4; j++) {
                bf16x8 bk = *(const bf16x8*)(&Ks[(j * 16 + mr) * 64 + kk * 32 + q * 8]);
                s[j] = __builtin_amdgcn_mfma_f32_16x16x32_bf16(aq, bk, s[j], 0, 0, 0);
            }
        }

        bool diag = (kt == qt);
#pragma unroll
        for (int j = 0; j < 4; j++)
#pragma unroll
            for (int r = 0; r < 4; r++) {
                float sv = s[j][r] * 0.125f;
                if (diag) {
                    int rowg = wv * 16 + q * 4 + r;
                    int colg = j * 16 + mr;
                    if (colg > rowg) sv = -1e30f;
                }
                s[j][r] = sv;
            }

#pragma unroll
        for (int r = 0; r < 4; r++) {
            float m0 = fmaxf(fmaxf(s[0][r], s[1][r]), fmaxf(s[2][r], s[3][r]));
#pragma unroll
            for (int msk = 1; msk < 16; msk <<= 1)
                m0 = fmaxf(m0, __shfl_xor(m0, msk, 64));
            float mn = fmaxf(m_run[r], m0);
            float alpha = __expf(m_run[r] - mn);
            m_run[r] = mn;
            float psum = 0.f;
#pragma unroll
            for (int j = 0; j < 4; j++) {
                float p = __expf(s[j][r] - mn);
                s[j][r] = p;
                psum += p;
            }
#pragma unroll
            for (int msk = 1; msk < 16; msk <<= 1)
                psum += __shfl_xor(psum, msk, 64);
            l_run[r] = l_run[r] * alpha + psum;
#pragma unroll
            for (int dt = 0; dt < 4; dt++)
                o_acc[dt][r] *= alpha;
        }

#pragma unroll
        for (int j = 0; j < 4; j++)
#pragma unroll
            for (int r = 0; r < 4; r++)
                Ps[wv * 1024 + (q * 4 + r) * 64 + j * 16 + mr] = f2bf(s[j][r]);
        __syncthreads();
#pragma unroll
        for (int kk = 0; kk < 2; kk++) {
            bf16x8 ap = *(const bf16x8*)(&Ps[wv * 1024 + mr * 64 + kk * 32 + q * 8]);
#pragma unroll
            for (int dt = 0; dt < 4; dt++) {
                bf16x8 bv = *(const bf16x8*)(&Vts[(dt * 16 + mr) * 64 + kk * 32 + q * 8]);
                o_acc[dt] = __builtin_amdgcn_mfma_f32_16x16x32_bf16(ap, bv, o_acc[dt], 0, 0, 0);
            }
        }
    }

#pragma unroll
    for (int r = 0; r < 4; r++) {
        float inv = 1.0f / l_run[r];
        int trow = qt * 64 + wv * 16 + q * 4 + r;
        size_t obase = (size_t)(b * T_ + trow) * D_ + h * HD_;
#pragma unroll
        for (int dt = 0; dt < 4; dt++)
            attn_out[obase + dt * 16 + mr] = f2bf(o_acc[dt][r] * inv);
    }
}

// ---------------------------------------------------------------------------
// Kernel 5: h = rmsnorm(xn,w2)*gamma+beta; rotations+silu; out = xn + r - h.
// Output dtype per flag (fp32 or bf16).
// ---------------------------------------------------------------------------
__global__ __launch_bounds__(256) void final_kernel(
    const float* __restrict__ xn,
    const float* __restrict__ gamma,
    const float* __restrict__ beta,
    const float* __restrict__ w2,
    const float* __restrict__ angles,
    const float* __restrict__ gate,
    const float* __restrict__ bias,
    const int* __restrict__ pi,
    const int* __restrict__ pj,
    const int* __restrict__ flag,
    void* __restrict__ outp)
{
    __shared__ float rbuf[D_];
    __shared__ float red[4];
    int row = blockIdx.x, t = threadIdx.x;
    int f = *flag;
    float eps = f ? 1.1920929e-7f : 0.0078125f;
    const float* xr = xn + (size_t)row * D_;
    float x4[4];
    float ss = 0.f;
#pragma unroll
    for (int c = 0; c < 4; c++) { x4[c] = xr[t * 4 + c]; ss += x4[c] * x4[c]; }
#pragma unroll
    for (int m = 32; m; m >>= 1) ss += __shfl_xor(ss, m, 64);
    int wv = t >> 6;
    if ((t & 63) == 0) red[wv] = ss;
    __syncthreads();
    float scale = rsqrtf((red[0] + red[1] + red[2] + red[3]) * (1.0f / D_) + eps);
    float hloc[4];
#pragma unroll
    for (int c = 0; c < 4; c++) {
        int e = t * 4 + c;
        float hv = x4[c] * scale * w2[e] * gamma[e] + beta[e];
        hloc[c] = hv;
        rbuf[e] = hv;
    }
    __syncthreads();
    for (int p = 0; p < NP_; p++) {
        // pairs within a pass are disjoint: thread t owns (pi[p][t], pj[p][t])
        float a = angles[p * P_ + t];
        float ca = __cosf(a), sa = __sinf(a);
        int ip = pi[p * P_ + t], jp = pj[p * P_ + t];
        float hi = rbuf[ip], hj = rbuf[jp];
        rbuf[ip] = hi * ca - hj * sa;
        rbuf[jp] = hi * sa + hj * ca;
        __syncthreads();
#pragma unroll
        for (int c = 0; c < 4; c++) {
            int e = t * 4 + c;
            float v = rbuf[e] * gate[p * D_ + e] + bias[p * D_ + e];
            rbuf[e] = v / (1.f + __expf(-v));   // silu
        }
        __syncthreads();
    }
#pragma unroll
    for (int c = 0; c < 4; c++) {
        int e = t * 4 + c;
        float ov = x4[c] + rbuf[e] - hloc[c];
        size_t idx = (size_t)row * D_ + e;
        if (f) ((float*)outp)[idx] = ov;
        else   ((__hip_bfloat16*)outp)[idx] = f2bf(ov);
    }
}

// ---------------------------------------------------------------------------
extern "C" void kernel_launch(void* const* d_in, const int* in_sizes, int n_in,
                              void* d_out, int out_size, void* d_ws, size_t ws_size,
                              hipStream_t stream)
{
    const void* x      = d_in[0];
    const void* gamma  = d_in[1];
    const void* beta   = d_in[2];
    const void* qkv_w  = d_in[3];
    const void* o_w    = d_in[4];
    const void* n1w    = d_in[5];
    const void* n2w    = d_in[6];
    const void* angles = d_in[7];
    const void* gate   = d_in[8];
    const void* bias   = d_in[9];
    const int* pi = (const int*)d_in[10];
    const int* pj = (const int*)d_in[11];

    const int M = B_ * T_;
    char* ws = (char*)d_ws;
    const size_t MB = 1u << 20;
    int*            flag  = (int*)ws;
    float* gf    = (float*)(ws +  4 * 1024);   // gamma  4KB
    float* bf    = (float*)(ws +  8 * 1024);   // beta   4KB
    float* n1f   = (float*)(ws + 12 * 1024);   // norm1  4KB
    float* n2f   = (float*)(ws + 16 * 1024);   // norm2  4KB
    float* angf  = (float*)(ws + 20 * 1024);   // angles 3KB
    float* gtf   = (float*)(ws + 24 * 1024);   // gate  12KB
    float* bif   = (float*)(ws + 40 * 1024);   // bias  12KB
    float*          xf32  = (float*)         (ws +  1 * MB);  // 16 MB [M,D] fp32
    __hip_bfloat16* wbf   = (__hip_bfloat16*)(ws + 17 * MB);  //  6 MB [3D,D]
    __hip_bfloat16* owbf  = (__hip_bfloat16*)(ws + 23 * MB);  //  2 MB [D,D]
    __hip_bfloat16* h1    = (__hip_bfloat16*)(ws + 25 * MB);  //  8 MB [M,D] bf16 (reused as attn out)
    __hip_bfloat16* qkv   = (__hip_bfloat16*)(ws + 33 * MB);  // 24 MB [M,3D]
    float*          xnew  = (float*)         (ws + 33 * MB);  // 16 MB, aliases dead qkv

    detect_kernel<<<1, 256, 0, stream>>>((const unsigned short*)x, flag);

    const int ND = M * D_;
    cvt32_kernel<<<(ND + 255) / 256, 256, 0, stream>>>(x, xf32, ND, flag);
    cvt16_kernel<<<(3 * D_ * D_ + 255) / 256, 256, 0, stream>>>(qkv_w, wbf, 3 * D_ * D_, flag);
    cvt16_kernel<<<(D_ * D_ + 255) / 256, 256, 0, stream>>>(o_w, owbf, D_ * D_, flag);
    cvt32_kernel<<<4, 256, 0, stream>>>(gamma, gf, D_, flag);
    cvt32_kernel<<<4, 256, 0, stream>>>(beta, bf, D_, flag);
    cvt32_kernel<<<4, 256, 0, stream>>>(n1w, n1f, D_, flag);
    cvt32_kernel<<<4, 256, 0, stream>>>(n2w, n2f, D_, flag);
    cvt32_kernel<<<3, 256, 0, stream>>>(angles, angf, NP_ * P_, flag);
    cvt32_kernel<<<12, 256, 0, stream>>>(gate, gtf, NP_ * D_, flag);
    cvt32_kernel<<<12, 256, 0, stream>>>(bias, bif, NP_ * D_, flag);

    rmsnorm1_kernel<<<M, 256, 0, stream>>>(xf32, gf, bf, n1f, flag, h1);

    gemm_bt_bf16_kernel<<<dim3(3 * D_ / 128, M / 128), 256, 0, stream>>>(
        h1, wbf, qkv, M, 3 * D_, D_);

    attn_kernel<<<dim3(T_ / 64, B_ * H_), 256, 0, stream>>>(qkv, h1);

    gemm_bt_resid_kernel<<<dim3(D_ / 128, M / 128), 256, 0, stream>>>(
        h1, owbf, xf32, xnew, M, D_, D_);

    final_kernel<<<M, 256, 0, stream>>>(xnew, gf, bf, n2f, angf, gtf, bif,
                                        pi, pj, flag, d_out);
}

// Round 4
// 321.706 us; speedup vs baseline: 1.2469x; 1.2469x over previous
//
#include <hip/hip_runtime.h>
#include <hip/hip_bf16.h>

#define B_ 2
#define T_ 2048
#define D_ 1024
#define H_ 16
#define HD_ 64
#define NP_ 3
#define P_ 256

typedef short bf16x8 __attribute__((ext_vector_type(8)));
typedef float f32x4 __attribute__((ext_vector_type(4)));

__device__ __forceinline__ float bf2f(__hip_bfloat16 v) { return __bfloat162float(v); }
__device__ __forceinline__ __hip_bfloat16 f2bf(float v) { return __float2bfloat16(v); }

#define GLOAD_LDS16(gp, lp) \
    __builtin_amdgcn_global_load_lds( \
        (const __attribute__((address_space(1))) void*)(gp), \
        (__attribute__((address_space(3))) void*)(lp), 16, 0, 0)

// ---------------------------------------------------------------------------
// Kernel 0: input dtype detect (fp32 reinterpreted as bf16 shows huge exps).
// ---------------------------------------------------------------------------
__global__ __launch_bounds__(256) void detect_kernel(
    const unsigned short* __restrict__ xs, int* __restrict__ flag)
{
    __shared__ int cnt;
    if (threadIdx.x == 0) cnt = 0;
    __syncthreads();
    int bad = 0;
    for (int i = threadIdx.x; i < 16384; i += 256) {
        int e = (xs[i] >> 7) & 0xFF;
        if (e >= 0xB8) bad++;
    }
    if (bad) atomicAdd(&cnt, bad);
    __syncthreads();
    if (threadIdx.x == 0) *flag = (cnt >= 8) ? 1 : 0;
}

// fp32-or-bf16 -> bf16 (weights for MFMA)
__global__ __launch_bounds__(256) void cvt16_kernel(
    const void* __restrict__ src, __hip_bfloat16* __restrict__ dst,
    int n, const int* __restrict__ flag)
{
    int i = blockIdx.x * 256 + threadIdx.x;
    if (i >= n) return;
    dst[i] = (*flag) ? f2bf(((const float*)src)[i])
                     : ((const __hip_bfloat16*)src)[i];
}

// all 7 small fp32 parameter arrays in one launch -> contiguous fp32 block
__global__ __launch_bounds__(256) void cvt_small_kernel(
    const void* __restrict__ g,  const void* __restrict__ b,
    const void* __restrict__ n1, const void* __restrict__ n2,
    const void* __restrict__ ang, const void* __restrict__ gt,
    const void* __restrict__ bi,
    float* __restrict__ dst, const int* __restrict__ flag)
{
    int i = blockIdx.x * 256 + threadIdx.x;
    if (i >= 11008) return;
    const void* src; int off;
    if      (i < 1024) { src = g;   off = i; }
    else if (i < 2048) { src = b;   off = i - 1024; }
    else if (i < 3072) { src = n1;  off = i - 2048; }
    else if (i < 4096) { src = n2;  off = i - 3072; }
    else if (i < 4864) { src = ang; off = i - 4096; }
    else if (i < 7936) { src = gt;  off = i - 4864; }
    else               { src = bi;  off = i - 7936; }
    dst[i] = (*flag) ? ((const float*)src)[off]
                     : bf2f(((const __hip_bfloat16*)src)[off]);
}

// ---------------------------------------------------------------------------
// Kernel 1: h = rmsnorm(x,w)*gamma+beta (bf16 out) and xcopy = x as fp32.
// Reads raw x per flag; fuses the former x-cvt kernel.
// ---------------------------------------------------------------------------
__global__ __launch_bounds__(256) void rmsnorm1_kernel(
    const void* __restrict__ xraw,
    const float* __restrict__ gamma,
    const float* __restrict__ beta,
    const float* __restrict__ w,
    const int* __restrict__ flag,
    __hip_bfloat16* __restrict__ out,
    float* __restrict__ xcopy)
{
    int row = blockIdx.x;
    int t = threadIdx.x;
    int f = *flag;
    float eps = f ? 1.1920929e-7f : 0.0078125f;
    float v[4];
    if (f) {
        const float4 xv = ((const float4*)((const float*)xraw + (size_t)row * D_))[t];
        v[0] = xv.x; v[1] = xv.y; v[2] = xv.z; v[3] = xv.w;
    } else {
        const __hip_bfloat16* xr = (const __hip_bfloat16*)xraw + (size_t)row * D_;
#pragma unroll
        for (int c = 0; c < 4; c++) v[c] = bf2f(xr[t * 4 + c]);
    }
    float ss = 0.f;
#pragma unroll
    for (int c = 0; c < 4; c++) ss += v[c] * v[c];
#pragma unroll
    for (int m = 32; m; m >>= 1) ss += __shfl_xor(ss, m, 64);
    __shared__ float red[4];
    int wv = t >> 6;
    if ((t & 63) == 0) red[wv] = ss;
    __syncthreads();
    float scale = rsqrtf((red[0] + red[1] + red[2] + red[3]) * (1.0f / D_) + eps);
#pragma unroll
    for (int c = 0; c < 4; c++) {
        int e = t * 4 + c;
        size_t idx = (size_t)row * D_ + e;
        xcopy[idx] = v[c];
        out[idx] = f2bf(v[c] * scale * w[e] * gamma[e] + beta[e]);
    }
}

// ---------------------------------------------------------------------------
// Kernel 2: C = A @ B^T bf16 out. 128x128, BK=32, global_load_lds width=16
// staging (m97 structure). Staging layout is forced contiguous (lane*16).
// ---------------------------------------------------------------------------
__global__ __launch_bounds__(256) void gemm_bt_bf16_kernel(
    const __hip_bfloat16* __restrict__ A,
    const __hip_bfloat16* __restrict__ Bm,
    __hip_bfloat16* __restrict__ C,
    int M, int N, int K)
{
    __shared__ __attribute__((aligned(16))) __hip_bfloat16 As[128 * 32];
    __shared__ __attribute__((aligned(16))) __hip_bfloat16 Bs[128 * 32];
    int tid = threadIdx.x;
    int bm = blockIdx.y, bn = blockIdx.x;
    int lane = tid & 63, wv = tid >> 6;
    int wm = wv >> 1, wn = wv & 1;
    int q = lane >> 4, mr = lane & 15;

    f32x4 acc[4][4] = {};

    for (int k0 = 0; k0 < K; k0 += 32) {
#pragma unroll
        for (int s = 0; s < 2; s++) {
            int e = (s * 256 + tid) * 8;
            int r = e >> 5, c = e & 31;
            GLOAD_LDS16(&A[(size_t)(bm * 128 + r) * K + k0 + c], &As[e]);
            GLOAD_LDS16(&Bm[(size_t)(bn * 128 + r) * K + k0 + c], &Bs[e]);
        }
        __syncthreads();
        bf16x8 af[4], bfr[4];
#pragma unroll
        for (int i = 0; i < 4; i++)
            af[i] = *(const bf16x8*)(&As[(wm * 64 + i * 16 + mr) * 32 + q * 8]);
#pragma unroll
        for (int j = 0; j < 4; j++)
            bfr[j] = *(const bf16x8*)(&Bs[(wn * 64 + j * 16 + mr) * 32 + q * 8]);
#pragma unroll
        for (int i = 0; i < 4; i++)
#pragma unroll
            for (int j = 0; j < 4; j++)
                acc[i][j] = __builtin_amdgcn_mfma_f32_16x16x32_bf16(af[i], bfr[j], acc[i][j], 0, 0, 0);
        __syncthreads();
    }

#pragma unroll
    for (int i = 0; i < 4; i++)
#pragma unroll
        for (int r = 0; r < 4; r++) {
            int m = bm * 128 + wm * 64 + i * 16 + q * 4 + r;
#pragma unroll
            for (int j = 0; j < 4; j++) {
                int n = bn * 128 + wn * 64 + j * 16 + mr;
                C[(size_t)m * N + n] = f2bf(acc[i][j][r]);
            }
        }
}

// Same GEMM, fp32 residual in + fp32 out (o-proj + residual spine).
__global__ __launch_bounds__(256) void gemm_bt_resid_kernel(
    const __hip_bfloat16* __restrict__ A,
    const __hip_bfloat16* __restrict__ Bm,
    const float* __restrict__ resid,
    float* __restrict__ C,
    int M, int N, int K)
{
    __shared__ __attribute__((aligned(16))) __hip_bfloat16 As[128 * 32];
    __shared__ __attribute__((aligned(16))) __hip_bfloat16 Bs[128 * 32];
    int tid = threadIdx.x;
    int bm = blockIdx.y, bn = blockIdx.x;
    int lane = tid & 63, wv = tid >> 6;
    int wm = wv >> 1, wn = wv & 1;
    int q = lane >> 4, mr = lane & 15;

    f32x4 acc[4][4] = {};

    for (int k0 = 0; k0 < K; k0 += 32) {
#pragma unroll
        for (int s = 0; s < 2; s++) {
            int e = (s * 256 + tid) * 8;
            int r = e >> 5, c = e & 31;
            GLOAD_LDS16(&A[(size_t)(bm * 128 + r) * K + k0 + c], &As[e]);
            GLOAD_LDS16(&Bm[(size_t)(bn * 128 + r) * K + k0 + c], &Bs[e]);
        }
        __syncthreads();
        bf16x8 af[4], bfr[4];
#pragma unroll
        for (int i = 0; i < 4; i++)
            af[i] = *(const bf16x8*)(&As[(wm * 64 + i * 16 + mr) * 32 + q * 8]);
#pragma unroll
        for (int j = 0; j < 4; j++)
            bfr[j] = *(const bf16x8*)(&Bs[(wn * 64 + j * 16 + mr) * 32 + q * 8]);
#pragma unroll
        for (int i = 0; i < 4; i++)
#pragma unroll
            for (int j = 0; j < 4; j++)
                acc[i][j] = __builtin_amdgcn_mfma_f32_16x16x32_bf16(af[i], bfr[j], acc[i][j], 0, 0, 0);
        __syncthreads();
    }

#pragma unroll
    for (int i = 0; i < 4; i++)
#pragma unroll
        for (int r = 0; r < 4; r++) {
            int m = bm * 128 + wm * 64 + i * 16 + q * 4 + r;
#pragma unroll
            for (int j = 0; j < 4; j++) {
                int n = bn * 128 + wn * 64 + j * 16 + mr;
                size_t idx = (size_t)m * N + n;
                C[idx] = resid[idx] + acc[i][j][r];
            }
        }
}

// ---------------------------------------------------------------------------
// Kernel 3: causal flash attention, swizzled LDS + register prefetch.
// All LDS tiles use phys_chunk = logical_chunk ^ (row & 7), chunk = 8 bf16.
// Consistency: swizzle key is always (row & 7) on both write and read side.
// ---------------------------------------------------------------------------
__global__ __launch_bounds__(256) void attn_kernel(
    const __hip_bfloat16* __restrict__ qkv,
    __hip_bfloat16* __restrict__ attn_out)
{
    __shared__ __attribute__((aligned(16))) __hip_bfloat16 Qs[64 * 64];
    __shared__ __attribute__((aligned(16))) __hip_bfloat16 Ks[64 * 64];
    __shared__ __attribute__((aligned(16))) __hip_bfloat16 Vts[64 * 64]; // [dim][key]
    __shared__ __attribute__((aligned(16))) __hip_bfloat16 Ps[4 * 16 * 64];

    int qt = (int)gridDim.x - 1 - (int)blockIdx.x;  // heavy tiles dispatch first
    int bh = blockIdx.y;
    int b = bh >> 4, h = bh & 15;
    int tid = threadIdx.x, lane = tid & 63, wv = tid >> 6;
    int q = lane >> 4, mr = lane & 15;
    int m8 = mr & 7;

    const size_t rs3 = 3 * D_;
    const __hip_bfloat16* qp = qkv + (size_t)(b * T_) * rs3 + h * HD_;
    const __hip_bfloat16* kp = qp + D_;
    const __hip_bfloat16* vp = qp + 2 * D_;

    // staging roles
    int sr = tid >> 2;              // row 0..63 (Q/K)
    int sc = (tid & 3) * 16;        // col start
    int lc0 = sc >> 3;              // logical chunk (0,2,4,6)
    int swk = sr & 7;
    int k2 = tid & 31;              // V: key-pair id
    int kk_ = k2 * 2;               // V: key (even)
    int dd = (tid >> 5) * 8;        // V: dim chunk base
    int vlc = kk_ >> 3, voff = kk_ & 7;

    // stage Q once (visible after first loop's 2nd barrier)
    {
        bf16x8 q0 = *(const bf16x8*)(qp + (size_t)(qt * 64 + sr) * rs3 + sc);
        bf16x8 q1 = *(const bf16x8*)(qp + (size_t)(qt * 64 + sr) * rs3 + sc + 8);
        *(bf16x8*)(&Qs[sr * 64 + ((lc0 ^ swk) * 8)]) = q0;
        *(bf16x8*)(&Qs[sr * 64 + (((lc0 + 1) ^ swk) * 8)]) = q1;
    }

    // prefetch tile 0 into registers
    bf16x8 kr0 = *(const bf16x8*)(kp + (size_t)sr * rs3 + sc);
    bf16x8 kr1 = *(const bf16x8*)(kp + (size_t)sr * rs3 + sc + 8);
    bf16x8 vr0 = *(const bf16x8*)(vp + (size_t)kk_ * rs3 + dd);
    bf16x8 vr1 = *(const bf16x8*)(vp + (size_t)(kk_ + 1) * rs3 + dd);

    float m_run[4], l_run[4];
    f32x4 o_acc[4] = {};
#pragma unroll
    for (int r = 0; r < 4; r++) { m_run[r] = -INFINITY; l_run[r] = 0.f; }

    for (int kt = 0; kt <= qt; kt++) {
        __syncthreads();   // all waves done reading previous Ks/Vts
        // staged regs -> LDS (swizzled, conflict-free)
        *(bf16x8*)(&Ks[sr * 64 + ((lc0 ^ swk) * 8)]) = kr0;
        *(bf16x8*)(&Ks[sr * 64 + (((lc0 + 1) ^ swk) * 8)]) = kr1;
        {
            unsigned int* vd = (unsigned int*)Vts;
#pragma unroll
            for (int i = 0; i < 8; i++) {
                unsigned int wd = ((unsigned int)(unsigned short)vr0[i]) |
                                  (((unsigned int)(unsigned short)vr1[i]) << 16);
                vd[((dd + i) * 64 + ((vlc ^ i) * 8 + voff)) >> 1] = wd;
            }
        }
        __syncthreads();   // staging visible
        if (kt < qt) {     // prefetch next tile; vmcnt consumed next iter top
            kr0 = *(const bf16x8*)(kp + (size_t)((kt + 1) * 64 + sr) * rs3 + sc);
            kr1 = *(const bf16x8*)(kp + (size_t)((kt + 1) * 64 + sr) * rs3 + sc + 8);
            vr0 = *(const bf16x8*)(vp + (size_t)((kt + 1) * 64 + kk_) * rs3 + dd);
            vr1 = *(const bf16x8*)(vp + (size_t)((kt + 1) * 64 + kk_ + 1) * rs3 + dd);
        }

        // S strip = Q[wv*16..+16) @ K^T
        f32x4 s[4] = {};
#pragma unroll
        for (int kk = 0; kk < 2; kk++) {
            bf16x8 aq = *(const bf16x8*)(&Qs[(wv * 16 + mr) * 64 + (((kk * 4 + q) ^ m8) * 8)]);
#pragma unroll
            for (int j = 0; j < 4; j++) {
                bf16x8 bk = *(const bf16x8*)(&Ks[(j * 16 + mr) * 64 + (((kk * 4 + q) ^ m8) * 8)]);
                s[j] = __builtin_amdgcn_mfma_f32_16x16x32_bf16(aq, bk, s[j], 0, 0, 0);
            }
        }

        bool diag = (kt == qt);
#pragma unroll
        for (int j = 0; j < 4; j++)
#pragma unroll
            for (int r = 0; r < 4; r++) {
                float sv = s[j][r] * 0.125f;   // 1/sqrt(64)
                if (diag) {
                    int rowg = wv * 16 + q * 4 + r;
                    int colg = j * 16 + mr;
                    if (colg > rowg) sv = -1e30f;
                }
                s[j][r] = sv;
            }

        // online softmax per query row (16 mr-lanes share a row at fixed q)
#pragma unroll
        for (int r = 0; r < 4; r++) {
            float m0 = fmaxf(fmaxf(s[0][r], s[1][r]), fmaxf(s[2][r], s[3][r]));
#pragma unroll
            for (int msk = 1; msk < 16; msk <<= 1)
                m0 = fmaxf(m0, __shfl_xor(m0, msk, 64));
            float mn = fmaxf(m_run[r], m0);
            float alpha = __expf(m_run[r] - mn);
            m_run[r] = mn;
            float psum = 0.f;
#pragma unroll
            for (int j = 0; j < 4; j++) {
                float p = __expf(s[j][r] - mn);
                s[j][r] = p;
                psum += p;
            }
#pragma unroll
            for (int msk = 1; msk < 16; msk <<= 1)
                psum += __shfl_xor(psum, msk, 64);
            l_run[r] = l_run[r] * alpha + psum;
#pragma unroll
            for (int dt = 0; dt < 4; dt++)
                o_acc[dt][r] *= alpha;
        }

        // P -> LDS (per-wave region, swizzled); no barrier needed (lgkmcnt)
#pragma unroll
        for (int j = 0; j < 4; j++)
#pragma unroll
            for (int r = 0; r < 4; r++) {
                int row = q * 4 + r;
                int pc = (2 * j + (mr >> 3)) ^ (row & 7);
                Ps[wv * 1024 + row * 64 + pc * 8 + (mr & 7)] = f2bf(s[j][r]);
            }
#pragma unroll
        for (int kk = 0; kk < 2; kk++) {
            bf16x8 ap = *(const bf16x8*)(&Ps[wv * 1024 + mr * 64 + (((kk * 4 + q) ^ m8) * 8)]);
#pragma unroll
            for (int dt = 0; dt < 4; dt++) {
                bf16x8 bv = *(const bf16x8*)(&Vts[(dt * 16 + mr) * 64 + (((kk * 4 + q) ^ m8) * 8)]);
                o_acc[dt] = __builtin_amdgcn_mfma_f32_16x16x32_bf16(ap, bv, o_acc[dt], 0, 0, 0);
            }
        }
    }

#pragma unroll
    for (int r = 0; r < 4; r++) {
        float inv = 1.0f / l_run[r];
        int trow = qt * 64 + wv * 16 + q * 4 + r;
        size_t obase = (size_t)(b * T_ + trow) * D_ + h * HD_;
#pragma unroll
        for (int dt = 0; dt < 4; dt++)
            attn_out[obase + dt * 16 + mr] = f2bf(o_acc[dt][r] * inv);
    }
}

// ---------------------------------------------------------------------------
// Kernel 5: h = rmsnorm(xn,w2)*gamma+beta; rotations+silu; out = xn + r - h.
// ---------------------------------------------------------------------------
__global__ __launch_bounds__(256) void final_kernel(
    const float* __restrict__ xn,
    const float* __restrict__ gamma,
    const float* __restrict__ beta,
    const float* __restrict__ w2,
    const float* __restrict__ angles,
    const float* __restrict__ gate,
    const float* __restrict__ bias,
    const int* __restrict__ pi,
    const int* __restrict__ pj,
    const int* __restrict__ flag,
    void* __restrict__ outp)
{
    __shared__ float rbuf[D_];
    __shared__ float red[4];
    int row = blockIdx.x, t = threadIdx.x;
    int f = *flag;
    float eps = f ? 1.1920929e-7f : 0.0078125f;
    const float* xr = xn + (size_t)row * D_;
    float x4[4];
    float ss = 0.f;
#pragma unroll
    for (int c = 0; c < 4; c++) { x4[c] = xr[t * 4 + c]; ss += x4[c] * x4[c]; }
#pragma unroll
    for (int m = 32; m; m >>= 1) ss += __shfl_xor(ss, m, 64);
    int wv = t >> 6;
    if ((t & 63) == 0) red[wv] = ss;
    __syncthreads();
    float scale = rsqrtf((red[0] + red[1] + red[2] + red[3]) * (1.0f / D_) + eps);
    float hloc[4];
#pragma unroll
    for (int c = 0; c < 4; c++) {
        int e = t * 4 + c;
        float hv = x4[c] * scale * w2[e] * gamma[e] + beta[e];
        hloc[c] = hv;
        rbuf[e] = hv;
    }
    __syncthreads();
    for (int p = 0; p < NP_; p++) {
        float a = angles[p * P_ + t];
        float ca = __cosf(a), sa = __sinf(a);
        int ip = pi[p * P_ + t], jp = pj[p * P_ + t];
        float hi = rbuf[ip], hj = rbuf[jp];
        rbuf[ip] = hi * ca - hj * sa;
        rbuf[jp] = hi * sa + hj * ca;
        __syncthreads();
#pragma unroll
        for (int c = 0; c < 4; c++) {
            int e = t * 4 + c;
            float v = rbuf[e] * gate[p * D_ + e] + bias[p * D_ + e];
            rbuf[e] = v / (1.f + __expf(-v));
        }
        __syncthreads();
    }
#pragma unroll
    for (int c = 0; c < 4; c++) {
        int e = t * 4 + c;
        float ov = x4[c] + rbuf[e] - hloc[c];
        size_t idx = (size_t)row * D_ + e;
        if (f) ((float*)outp)[idx] = ov;
        else   ((__hip_bfloat16*)outp)[idx] = f2bf(ov);
    }
}

// ---------------------------------------------------------------------------
extern "C" void kernel_launch(void* const* d_in, const int* in_sizes, int n_in,
                              void* d_out, int out_size, void* d_ws, size_t ws_size,
                              hipStream_t stream)
{
    const void* x      = d_in[0];
    const void* gamma  = d_in[1];
    const void* beta   = d_in[2];
    const void* qkv_w  = d_in[3];
    const void* o_w    = d_in[4];
    const void* n1w    = d_in[5];
    const void* n2w    = d_in[6];
    const void* angles = d_in[7];
    const void* gate   = d_in[8];
    const void* bias   = d_in[9];
    const int* pi = (const int*)d_in[10];
    const int* pj = (const int*)d_in[11];

    const int M = B_ * T_;
    char* ws = (char*)d_ws;
    const size_t MB = 1u << 20;
    int*   flag  = (int*)ws;
    float* smalls = (float*)(ws + 4096);       // 11008 floats, 44 KB
    float* gf   = smalls;
    float* bf   = smalls + 1024;
    float* n1f  = smalls + 2048;
    float* n2f  = smalls + 3072;
    float* angf = smalls + 4096;
    float* gtf  = smalls + 4864;
    float* bif  = smalls + 7936;
    float*          xf32 = (float*)         (ws +  1 * MB);  // 16 MB [M,D]
    __hip_bfloat16* wbf  = (__hip_bfloat16*)(ws + 17 * MB);  //  6 MB [3D,D]
    __hip_bfloat16* owbf = (__hip_bfloat16*)(ws + 23 * MB);  //  2 MB [D,D]
    __hip_bfloat16* h1   = (__hip_bfloat16*)(ws + 25 * MB);  //  8 MB [M,D] (h then attn-out)
    __hip_bfloat16* qkv  = (__hip_bfloat16*)(ws + 33 * MB);  // 24 MB [M,3D]
    float*          xnew = (float*)         (ws + 33 * MB);  // 16 MB, aliases dead qkv

    detect_kernel<<<1, 256, 0, stream>>>((const unsigned short*)x, flag);

    cvt_small_kernel<<<43, 256, 0, stream>>>(gamma, beta, n1w, n2w, angles, gate, bias,
                                             smalls, flag);
    cvt16_kernel<<<(3 * D_ * D_ + 255) / 256, 256, 0, stream>>>(qkv_w, wbf, 3 * D_ * D_, flag);
    cvt16_kernel<<<(D_ * D_ + 255) / 256, 256, 0, stream>>>(o_w, owbf, D_ * D_, flag);

    rmsnorm1_kernel<<<M, 256, 0, stream>>>(x, gf, bf, n1f, flag, h1, xf32);

    gemm_bt_bf16_kernel<<<dim3(3 * D_ / 128, M / 128), 256, 0, stream>>>(
        h1, wbf, qkv, M, 3 * D_, D_);

    attn_kernel<<<dim3(T_ / 64, B_ * H_), 256, 0, stream>>>(qkv, h1);

    gemm_bt_resid_kernel<<<dim3(D_ / 128, M / 128), 256, 0, stream>>>(
        h1, owbf, xf32, xnew, M, D_, D_);

    final_kernel<<<M, 256, 0, stream>>>(xnew, gf, bf, n2f, angf, gtf, bif,
                                        pi, pj, flag, d_out);
}

// Round 5
// 267.470 us; speedup vs baseline: 1.4997x; 1.2028x over previous
//
#include <hip/hip_runtime.h>
#include <hip/hip_bf16.h>

#define B_ 2
#define T_ 2048
#define D_ 1024
#define H_ 16
#define HD_ 64
#define NP_ 3
#define P_ 256

typedef short bf16x8 __attribute__((ext_vector_type(8)));
typedef float f32x4 __attribute__((ext_vector_type(4)));

__device__ __forceinline__ float bf2f(__hip_bfloat16 v) { return __bfloat162float(v); }
__device__ __forceinline__ __hip_bfloat16 f2bf(float v) { return __float2bfloat16(v); }

#define GLOAD_LDS16(gp, lp) \
    __builtin_amdgcn_global_load_lds( \
        (const __attribute__((address_space(1))) void*)(gp), \
        (__attribute__((address_space(3))) void*)(lp), 16, 0, 0)

// ---------------------------------------------------------------------------
// Kernel 0: input dtype detect (fp32 reinterpreted as bf16 shows huge exps).
// ---------------------------------------------------------------------------
__global__ __launch_bounds__(256) void detect_kernel(
    const unsigned short* __restrict__ xs, int* __restrict__ flag)
{
    __shared__ int cnt;
    if (threadIdx.x == 0) cnt = 0;
    __syncthreads();
    int bad = 0;
    for (int i = threadIdx.x; i < 16384; i += 256) {
        int e = (xs[i] >> 7) & 0xFF;
        if (e >= 0xB8) bad++;
    }
    if (bad) atomicAdd(&cnt, bad);
    __syncthreads();
    if (threadIdx.x == 0) *flag = (cnt >= 8) ? 1 : 0;
}

// fp32-or-bf16 -> bf16 (weights for MFMA)
__global__ __launch_bounds__(256) void cvt16_kernel(
    const void* __restrict__ src, __hip_bfloat16* __restrict__ dst,
    int n, const int* __restrict__ flag)
{
    int i = blockIdx.x * 256 + threadIdx.x;
    if (i >= n) return;
    dst[i] = (*flag) ? f2bf(((const float*)src)[i])
                     : ((const __hip_bfloat16*)src)[i];
}

// all 7 small fp32 parameter arrays in one launch -> contiguous fp32 block
__global__ __launch_bounds__(256) void cvt_small_kernel(
    const void* __restrict__ g,  const void* __restrict__ b,
    const void* __restrict__ n1, const void* __restrict__ n2,
    const void* __restrict__ ang, const void* __restrict__ gt,
    const void* __restrict__ bi,
    float* __restrict__ dst, const int* __restrict__ flag)
{
    int i = blockIdx.x * 256 + threadIdx.x;
    if (i >= 11008) return;
    const void* src; int off;
    if      (i < 1024) { src = g;   off = i; }
    else if (i < 2048) { src = b;   off = i - 1024; }
    else if (i < 3072) { src = n1;  off = i - 2048; }
    else if (i < 4096) { src = n2;  off = i - 3072; }
    else if (i < 4864) { src = ang; off = i - 4096; }
    else if (i < 7936) { src = gt;  off = i - 4864; }
    else               { src = bi;  off = i - 7936; }
    dst[i] = (*flag) ? ((const float*)src)[off]
                     : bf2f(((const __hip_bfloat16*)src)[off]);
}

// ---------------------------------------------------------------------------
// Kernel 1: h = rmsnorm(x,w)*gamma+beta (bf16 out) and xcopy = x as fp32.
// ---------------------------------------------------------------------------
__global__ __launch_bounds__(256) void rmsnorm1_kernel(
    const void* __restrict__ xraw,
    const float* __restrict__ gamma,
    const float* __restrict__ beta,
    const float* __restrict__ w,
    const int* __restrict__ flag,
    __hip_bfloat16* __restrict__ out,
    float* __restrict__ xcopy)
{
    int row = blockIdx.x;
    int t = threadIdx.x;
    int f = *flag;
    float eps = f ? 1.1920929e-7f : 0.0078125f;
    float v[4];
    if (f) {
        const float4 xv = ((const float4*)((const float*)xraw + (size_t)row * D_))[t];
        v[0] = xv.x; v[1] = xv.y; v[2] = xv.z; v[3] = xv.w;
    } else {
        const __hip_bfloat16* xr = (const __hip_bfloat16*)xraw + (size_t)row * D_;
#pragma unroll
        for (int c = 0; c < 4; c++) v[c] = bf2f(xr[t * 4 + c]);
    }
    float ss = 0.f;
#pragma unroll
    for (int c = 0; c < 4; c++) ss += v[c] * v[c];
#pragma unroll
    for (int m = 32; m; m >>= 1) ss += __shfl_xor(ss, m, 64);
    __shared__ float red[4];
    int wv = t >> 6;
    if ((t & 63) == 0) red[wv] = ss;
    __syncthreads();
    float scale = rsqrtf((red[0] + red[1] + red[2] + red[3]) * (1.0f / D_) + eps);
#pragma unroll
    for (int c = 0; c < 4; c++) {
        int e = t * 4 + c;
        size_t idx = (size_t)row * D_ + e;
        xcopy[idx] = v[c];
        out[idx] = f2bf(v[c] * scale * w[e] * gamma[e] + beta[e]);
    }
}

// ---------------------------------------------------------------------------
// Kernel 2: C = A @ B^T bf16 out. 128x128, BK=32, global_load_lds width=16.
// ---------------------------------------------------------------------------
__global__ __launch_bounds__(256) void gemm_bt_bf16_kernel(
    const __hip_bfloat16* __restrict__ A,
    const __hip_bfloat16* __restrict__ Bm,
    __hip_bfloat16* __restrict__ C,
    int M, int N, int K)
{
    __shared__ __attribute__((aligned(16))) __hip_bfloat16 As[128 * 32];
    __shared__ __attribute__((aligned(16))) __hip_bfloat16 Bs[128 * 32];
    int tid = threadIdx.x;
    int bm = blockIdx.y, bn = blockIdx.x;
    int lane = tid & 63, wv = tid >> 6;
    int wm = wv >> 1, wn = wv & 1;
    int q = lane >> 4, mr = lane & 15;

    f32x4 acc[4][4] = {};

    for (int k0 = 0; k0 < K; k0 += 32) {
#pragma unroll
        for (int s = 0; s < 2; s++) {
            int e = (s * 256 + tid) * 8;
            int r = e >> 5, c = e & 31;
            GLOAD_LDS16(&A[(size_t)(bm * 128 + r) * K + k0 + c], &As[e]);
            GLOAD_LDS16(&Bm[(size_t)(bn * 128 + r) * K + k0 + c], &Bs[e]);
        }
        __syncthreads();
        bf16x8 af[4], bfr[4];
#pragma unroll
        for (int i = 0; i < 4; i++)
            af[i] = *(const bf16x8*)(&As[(wm * 64 + i * 16 + mr) * 32 + q * 8]);
#pragma unroll
        for (int j = 0; j < 4; j++)
            bfr[j] = *(const bf16x8*)(&Bs[(wn * 64 + j * 16 + mr) * 32 + q * 8]);
#pragma unroll
        for (int i = 0; i < 4; i++)
#pragma unroll
            for (int j = 0; j < 4; j++)
                acc[i][j] = __builtin_amdgcn_mfma_f32_16x16x32_bf16(af[i], bfr[j], acc[i][j], 0, 0, 0);
        __syncthreads();
    }

#pragma unroll
    for (int i = 0; i < 4; i++)
#pragma unroll
        for (int r = 0; r < 4; r++) {
            int m = bm * 128 + wm * 64 + i * 16 + q * 4 + r;
#pragma unroll
            for (int j = 0; j < 4; j++) {
                int n = bn * 128 + wn * 64 + j * 16 + mr;
                C[(size_t)m * N + n] = f2bf(acc[i][j][r]);
            }
        }
}

// Same GEMM, fp32 residual in + fp32 out (o-proj + residual spine).
__global__ __launch_bounds__(256) void gemm_bt_resid_kernel(
    const __hip_bfloat16* __restrict__ A,
    const __hip_bfloat16* __restrict__ Bm,
    const float* __restrict__ resid,
    float* __restrict__ C,
    int M, int N, int K)
{
    __shared__ __attribute__((aligned(16))) __hip_bfloat16 As[128 * 32];
    __shared__ __attribute__((aligned(16))) __hip_bfloat16 Bs[128 * 32];
    int tid = threadIdx.x;
    int bm = blockIdx.y, bn = blockIdx.x;
    int lane = tid & 63, wv = tid >> 6;
    int wm = wv >> 1, wn = wv & 1;
    int q = lane >> 4, mr = lane & 15;

    f32x4 acc[4][4] = {};

    for (int k0 = 0; k0 < K; k0 += 32) {
#pragma unroll
        for (int s = 0; s < 2; s++) {
            int e = (s * 256 + tid) * 8;
            int r = e >> 5, c = e & 31;
            GLOAD_LDS16(&A[(size_t)(bm * 128 + r) * K + k0 + c], &As[e]);
            GLOAD_LDS16(&Bm[(size_t)(bn * 128 + r) * K + k0 + c], &Bs[e]);
        }
        __syncthreads();
        bf16x8 af[4], bfr[4];
#pragma unroll
        for (int i = 0; i < 4; i++)
            af[i] = *(const bf16x8*)(&As[(wm * 64 + i * 16 + mr) * 32 + q * 8]);
#pragma unroll
        for (int j = 0; j < 4; j++)
            bfr[j] = *(const bf16x8*)(&Bs[(wn * 64 + j * 16 + mr) * 32 + q * 8]);
#pragma unroll
        for (int i = 0; i < 4; i++)
#pragma unroll
            for (int j = 0; j < 4; j++)
                acc[i][j] = __builtin_amdgcn_mfma_f32_16x16x32_bf16(af[i], bfr[j], acc[i][j], 0, 0, 0);
        __syncthreads();
    }

#pragma unroll
    for (int i = 0; i < 4; i++)
#pragma unroll
        for (int r = 0; r < 4; r++) {
            int m = bm * 128 + wm * 64 + i * 16 + q * 4 + r;
#pragma unroll
            for (int j = 0; j < 4; j++) {
                int n = bn * 128 + wn * 64 + j * 16 + mr;
                size_t idx = (size_t)m * N + n;
                C[idx] = resid[idx] + acc[i][j][r];
            }
        }
}

// ---------------------------------------------------------------------------
// Kernel 3: causal flash attention.
//  - paired query tiles (qt0=31-z, qt1=z): every block does exactly 33 iters
//  - K/V double-buffered in LDS, ONE barrier per iteration
//  - Q fragments in registers (wave-private), prefetched for segment 1
//  - XOR chunk swizzle (round-4 verified, 0 conflicts)
// ---------------------------------------------------------------------------
__global__ __launch_bounds__(256) void attn_kernel(
    const __hip_bfloat16* __restrict__ qkv,
    __hip_bfloat16* __restrict__ attn_out)
{
    __shared__ __attribute__((aligned(16))) __hip_bfloat16 Ks[2][64 * 64];
    __shared__ __attribute__((aligned(16))) __hip_bfloat16 Vts[2][64 * 64]; // [dim][key]
    __shared__ __attribute__((aligned(16))) __hip_bfloat16 Ps[4 * 16 * 64];

    int z = blockIdx.x;                 // 0..15
    int qt0 = 31 - z, qt1 = z;          // uniform 33 iterations per block
    int bh = blockIdx.y;
    int b = bh >> 4, h = bh & 15;
    int tid = threadIdx.x, lane = tid & 63, wv = tid >> 6;
    int q = lane >> 4, mr = lane & 15;
    int m8 = mr & 7;

    const size_t rs3 = 3 * D_;
    const __hip_bfloat16* qp = qkv + (size_t)(b * T_) * rs3 + h * HD_;
    const __hip_bfloat16* kp = qp + D_;
    const __hip_bfloat16* vp = qp + 2 * D_;

    // staging roles
    int sr = tid >> 2;              // K row (key) 0..63
    int sc = (tid & 3) * 16;        // K col start
    int lc0 = sc >> 3;
    int swk = sr & 7;
    int kk_ = (tid & 31) * 2;       // V key (even)
    int dd = (tid >> 5) * 8;        // V dim chunk base
    int vlc = kk_ >> 3, voff = kk_ & 7;

    // Q fragments in registers (wave-private 16 rows of current tile)
    bf16x8 aq0, aq1, aqn0, aqn1;
    {
        const __hip_bfloat16* qrow = qp + (size_t)(qt0 * 64 + wv * 16 + mr) * rs3;
        aq0 = *(const bf16x8*)(qrow + q * 8);
        aq1 = *(const bf16x8*)(qrow + 32 + q * 8);
    }

    // prefetch K/V tile 0 and stage into buffer 0
    bf16x8 kr0 = *(const bf16x8*)(kp + (size_t)sr * rs3 + sc);
    bf16x8 kr1 = *(const bf16x8*)(kp + (size_t)sr * rs3 + sc + 8);
    bf16x8 vr0 = *(const bf16x8*)(vp + (size_t)kk_ * rs3 + dd);
    bf16x8 vr1 = *(const bf16x8*)(vp + (size_t)(kk_ + 1) * rs3 + dd);
    *(bf16x8*)(&Ks[0][sr * 64 + ((lc0 ^ swk) * 8)]) = kr0;
    *(bf16x8*)(&Ks[0][sr * 64 + (((lc0 + 1) ^ swk) * 8)]) = kr1;
    {
        unsigned int* vd = (unsigned int*)&Vts[0][0];
#pragma unroll
        for (int i = 0; i < 8; i++) {
            unsigned int wd = ((unsigned int)(unsigned short)vr0[i]) |
                              (((unsigned int)(unsigned short)vr1[i]) << 16);
            vd[((dd + i) * 64 + ((vlc ^ i) * 8 + voff)) >> 1] = wd;
        }
    }
    __syncthreads();

    float m_run[4], l_run[4];
    f32x4 o_acc[4] = {};
#pragma unroll
    for (int r = 0; r < 4; r++) { m_run[r] = -INFINITY; l_run[r] = 0.f; }

    for (int s = 0; s <= 32; s++) {
        int seg1 = (s > qt0);
        int kt = seg1 ? (s - qt0 - 1) : s;
        int qt = seg1 ? qt1 : qt0;
        int buf = s & 1;

        // issue prefetches for step s+1 (consumed at end of this iter)
        if (s < 32) {
            int ktn = (s + 1 > qt0) ? (s - qt0) : (s + 1);
            kr0 = *(const bf16x8*)(kp + (size_t)(ktn * 64 + sr) * rs3 + sc);
            kr1 = *(const bf16x8*)(kp + (size_t)(ktn * 64 + sr) * rs3 + sc + 8);
            vr0 = *(const bf16x8*)(vp + (size_t)(ktn * 64 + kk_) * rs3 + dd);
            vr1 = *(const bf16x8*)(vp + (size_t)(ktn * 64 + kk_ + 1) * rs3 + dd);
        }
        if (s == qt0) {   // Q fragments for segment 1, one iter early
            const __hip_bfloat16* qrow = qp + (size_t)(qt1 * 64 + wv * 16 + mr) * rs3;
            aqn0 = *(const bf16x8*)(qrow + q * 8);
            aqn1 = *(const bf16x8*)(qrow + 32 + q * 8);
        }

        // S strip = Q[wv*16..+16) @ K^T
        f32x4 sv[4] = {};
        {
            const __hip_bfloat16* Kb = &Ks[buf][0];
#pragma unroll
            for (int j = 0; j < 4; j++)
                sv[j] = __builtin_amdgcn_mfma_f32_16x16x32_bf16(aq0,
                    *(const bf16x8*)(&Kb[(j * 16 + mr) * 64 + ((q ^ m8) * 8)]), sv[j], 0, 0, 0);
#pragma unroll
            for (int j = 0; j < 4; j++)
                sv[j] = __builtin_amdgcn_mfma_f32_16x16x32_bf16(aq1,
                    *(const bf16x8*)(&Kb[(j * 16 + mr) * 64 + (((4 + q) ^ m8) * 8)]), sv[j], 0, 0, 0);
        }

        bool diag = (kt == qt);
#pragma unroll
        for (int j = 0; j < 4; j++)
#pragma unroll
            for (int r = 0; r < 4; r++) {
                float x = sv[j][r] * 0.125f;   // 1/sqrt(64)
                if (diag) {
                    int rowg = wv * 16 + q * 4 + r;
                    int colg = j * 16 + mr;
                    if (colg > rowg) x = -1e30f;
                }
                sv[j][r] = x;
            }

        // online softmax per query row (16 mr-lanes share a row at fixed q)
#pragma unroll
        for (int r = 0; r < 4; r++) {
            float m0 = fmaxf(fmaxf(sv[0][r], sv[1][r]), fmaxf(sv[2][r], sv[3][r]));
#pragma unroll
            for (int msk = 1; msk < 16; msk <<= 1)
                m0 = fmaxf(m0, __shfl_xor(m0, msk, 64));
            float mn = fmaxf(m_run[r], m0);
            float alpha = __expf(m_run[r] - mn);
            m_run[r] = mn;
            float psum = 0.f;
#pragma unroll
            for (int j = 0; j < 4; j++) {
                float p = __expf(sv[j][r] - mn);
                sv[j][r] = p;
                psum += p;
            }
#pragma unroll
            for (int msk = 1; msk < 16; msk <<= 1)
                psum += __shfl_xor(psum, msk, 64);
            l_run[r] = l_run[r] * alpha + psum;
#pragma unroll
            for (int dt = 0; dt < 4; dt++)
                o_acc[dt][r] *= alpha;
        }

        // P -> LDS (per-wave region, swizzled; lgkmcnt ordering, no barrier)
#pragma unroll
        for (int j = 0; j < 4; j++)
#pragma unroll
            for (int r = 0; r < 4; r++) {
                int row = q * 4 + r;
                int pc = (2 * j + (mr >> 3)) ^ (row & 7);
                Ps[wv * 1024 + row * 64 + pc * 8 + (mr & 7)] = f2bf(sv[j][r]);
            }
#pragma unroll
        for (int kk = 0; kk < 2; kk++) {
            bf16x8 ap = *(const bf16x8*)(&Ps[wv * 1024 + mr * 64 + (((kk * 4 + q) ^ m8) * 8)]);
#pragma unroll
            for (int dt = 0; dt < 4; dt++) {
                bf16x8 bv = *(const bf16x8*)(&Vts[buf][(dt * 16 + mr) * 64 + (((kk * 4 + q) ^ m8) * 8)]);
                o_acc[dt] = __builtin_amdgcn_mfma_f32_16x16x32_bf16(ap, bv, o_acc[dt], 0, 0, 0);
            }
        }

        // stage next tile into the other buffer (vmcnt hidden by compute)
        if (s < 32) {
            *(bf16x8*)(&Ks[buf ^ 1][sr * 64 + ((lc0 ^ swk) * 8)]) = kr0;
            *(bf16x8*)(&Ks[buf ^ 1][sr * 64 + (((lc0 + 1) ^ swk) * 8)]) = kr1;
            unsigned int* vd = (unsigned int*)&Vts[buf ^ 1][0];
#pragma unroll
            for (int i = 0; i < 8; i++) {
                unsigned int wd = ((unsigned int)(unsigned short)vr0[i]) |
                                  (((unsigned int)(unsigned short)vr1[i]) << 16);
                vd[((dd + i) * 64 + ((vlc ^ i) * 8 + voff)) >> 1] = wd;
            }
        }
        __syncthreads();

        if (s == qt0) {
            // segment 0 done: store output, reset state, swap Q frags
#pragma unroll
            for (int r = 0; r < 4; r++) {
                float inv = 1.0f / l_run[r];
                int trow = qt0 * 64 + wv * 16 + q * 4 + r;
                size_t obase = (size_t)(b * T_ + trow) * D_ + h * HD_;
#pragma unroll
                for (int dt = 0; dt < 4; dt++)
                    attn_out[obase + dt * 16 + mr] = f2bf(o_acc[dt][r] * inv);
            }
#pragma unroll
            for (int r = 0; r < 4; r++) { m_run[r] = -INFINITY; l_run[r] = 0.f; }
#pragma unroll
            for (int dt = 0; dt < 4; dt++) o_acc[dt] = (f32x4){0.f, 0.f, 0.f, 0.f};
            aq0 = aqn0; aq1 = aqn1;
        }
    }

    // segment 1 output
#pragma unroll
    for (int r = 0; r < 4; r++) {
        float inv = 1.0f / l_run[r];
        int trow = qt1 * 64 + wv * 16 + q * 4 + r;
        size_t obase = (size_t)(b * T_ + trow) * D_ + h * HD_;
#pragma unroll
        for (int dt = 0; dt < 4; dt++)
            attn_out[obase + dt * 16 + mr] = f2bf(o_acc[dt][r] * inv);
    }
}

// ---------------------------------------------------------------------------
// Kernel 5: h = rmsnorm(xn,w2)*gamma+beta; rotations+silu; out = xn + r - h.
// ---------------------------------------------------------------------------
__global__ __launch_bounds__(256) void final_kernel(
    const float* __restrict__ xn,
    const float* __restrict__ gamma,
    const float* __restrict__ beta,
    const float* __restrict__ w2,
    const float* __restrict__ angles,
    const float* __restrict__ gate,
    const float* __restrict__ bias,
    const int* __restrict__ pi,
    const int* __restrict__ pj,
    const int* __restrict__ flag,
    void* __restrict__ outp)
{
    __shared__ float rbuf[D_];
    __shared__ float red[4];
    int row = blockIdx.x, t = threadIdx.x;
    int f = *flag;
    float eps = f ? 1.1920929e-7f : 0.0078125f;
    const float* xr = xn + (size_t)row * D_;
    float x4[4];
    float ss = 0.f;
#pragma unroll
    for (int c = 0; c < 4; c++) { x4[c] = xr[t * 4 + c]; ss += x4[c] * x4[c]; }
#pragma unroll
    for (int m = 32; m; m >>= 1) ss += __shfl_xor(ss, m, 64);
    int wv = t >> 6;
    if ((t & 63) == 0) red[wv] = ss;
    __syncthreads();
    float scale = rsqrtf((red[0] + red[1] + red[2] + red[3]) * (1.0f / D_) + eps);
    float hloc[4];
#pragma unroll
    for (int c = 0; c < 4; c++) {
        int e = t * 4 + c;
        float hv = x4[c] * scale * w2[e] * gamma[e] + beta[e];
        hloc[c] = hv;
        rbuf[e] = hv;
    }
    __syncthreads();
    for (int p = 0; p < NP_; p++) {
        float a = angles[p * P_ + t];
        float ca = __cosf(a), sa = __sinf(a);
        int ip = pi[p * P_ + t], jp = pj[p * P_ + t];
        float hi = rbuf[ip], hj = rbuf[jp];
        rbuf[ip] = hi * ca - hj * sa;
        rbuf[jp] = hi * sa + hj * ca;
        __syncthreads();
#pragma unroll
        for (int c = 0; c < 4; c++) {
            int e = t * 4 + c;
            float v = rbuf[e] * gate[p * D_ + e] + bias[p * D_ + e];
            rbuf[e] = v / (1.f + __expf(-v));
        }
        __syncthreads();
    }
#pragma unroll
    for (int c = 0; c < 4; c++) {
        int e = t * 4 + c;
        float ov = x4[c] + rbuf[e] - hloc[c];
        size_t idx = (size_t)row * D_ + e;
        if (f) ((float*)outp)[idx] = ov;
        else   ((__hip_bfloat16*)outp)[idx] = f2bf(ov);
    }
}

// ---------------------------------------------------------------------------
extern "C" void kernel_launch(void* const* d_in, const int* in_sizes, int n_in,
                              void* d_out, int out_size, void* d_ws, size_t ws_size,
                              hipStream_t stream)
{
    const void* x      = d_in[0];
    const void* gamma  = d_in[1];
    const void* beta   = d_in[2];
    const void* qkv_w  = d_in[3];
    const void* o_w    = d_in[4];
    const void* n1w    = d_in[5];
    const void* n2w    = d_in[6];
    const void* angles = d_in[7];
    const void* gate   = d_in[8];
    const void* bias   = d_in[9];
    const int* pi = (const int*)d_in[10];
    const int* pj = (const int*)d_in[11];

    const int M = B_ * T_;
    char* ws = (char*)d_ws;
    const size_t MB = 1u << 20;
    int*   flag  = (int*)ws;
    float* smalls = (float*)(ws + 4096);       // 11008 floats, 44 KB
    float* gf   = smalls;
    float* bf   = smalls + 1024;
    float* n1f  = smalls + 2048;
    float* n2f  = smalls + 3072;
    float* angf = smalls + 4096;
    float* gtf  = smalls + 4864;
    float* bif  = smalls + 7936;
    float*          xf32 = (float*)         (ws +  1 * MB);  // 16 MB [M,D]
    __hip_bfloat16* wbf  = (__hip_bfloat16*)(ws + 17 * MB);  //  6 MB [3D,D]
    __hip_bfloat16* owbf = (__hip_bfloat16*)(ws + 23 * MB);  //  2 MB [D,D]
    __hip_bfloat16* h1   = (__hip_bfloat16*)(ws + 25 * MB);  //  8 MB [M,D] (h then attn-out)
    __hip_bfloat16* qkv  = (__hip_bfloat16*)(ws + 33 * MB);  // 24 MB [M,3D]
    float*          xnew = (float*)         (ws + 33 * MB);  // 16 MB, aliases dead qkv

    detect_kernel<<<1, 256, 0, stream>>>((const unsigned short*)x, flag);

    cvt_small_kernel<<<43, 256, 0, stream>>>(gamma, beta, n1w, n2w, angles, gate, bias,
                                             smalls, flag);
    cvt16_kernel<<<(3 * D_ * D_ + 255) / 256, 256, 0, stream>>>(qkv_w, wbf, 3 * D_ * D_, flag);
    cvt16_kernel<<<(D_ * D_ + 255) / 256, 256, 0, stream>>>(o_w, owbf, D_ * D_, flag);

    rmsnorm1_kernel<<<M, 256, 0, stream>>>(x, gf, bf, n1f, flag, h1, xf32);

    gemm_bt_bf16_kernel<<<dim3(3 * D_ / 128, M / 128), 256, 0, stream>>>(
        h1, wbf, qkv, M, 3 * D_, D_);

    attn_kernel<<<dim3(16, B_ * H_), 256, 0, stream>>>(qkv, h1);

    gemm_bt_resid_kernel<<<dim3(D_ / 128, M / 128), 256, 0, stream>>>(
        h1, owbf, xf32, xnew, M, D_, D_);

    final_kernel<<<M, 256, 0, stream>>>(xnew, gf, bf, n2f, angf, gtf, bif,
                                        pi, pj, flag, d_out);
}